// Round 4
// baseline (313.495 us; speedup 1.0000x reference)
//
#include <hip/hip_runtime.h>
#include <math.h>

#define NB    15
#define BWID  129
#define HOP   64
#define NFREQ 1025
#define EMB   128
#define MLP   512
#define OUTC  516
#define O2    1032
#define BATCH 2
#define TLEN  2048
#define REIM  2
#define CCH   2
#define RTOT  (BATCH*NB*TLEN)

typedef _Float16 half8 __attribute__((ext_vector_type(8)));
typedef _Float16 half4 __attribute__((ext_vector_type(4)));
typedef _Float16 half2_ __attribute__((ext_vector_type(2)));
typedef float    floatx4 __attribute__((ext_vector_type(4)));

#define GLOAD_LDS(gsrc, ldst) \
  __builtin_amdgcn_global_load_lds((const __attribute__((address_space(1))) unsigned int*)(gsrc), \
                                   (__attribute__((address_space(3))) unsigned int*)(ldst), 16, 0, 0)

// ---------------- LayerNorm: one wave per row of 128, f16 out ----------------
__global__ __launch_bounds__(256) void ln_kernel(const float* __restrict__ q,
                                                 const float* __restrict__ gamma,
                                                 const float* __restrict__ beta,
                                                 _Float16* __restrict__ qn)
{
    int row  = blockIdx.x * 4 + (threadIdx.x >> 6);
    int lane = threadIdx.x & 63;
    int n    = (row / TLEN) % NB;

    const float2* src = (const float2*)(q + (size_t)row * EMB);
    float2 v = src[lane];
    float s  = v.x + v.y;
    float s2 = v.x * v.x + v.y * v.y;
    #pragma unroll
    for (int off = 1; off < 64; off <<= 1) {
        s  += __shfl_xor(s,  off);
        s2 += __shfl_xor(s2, off);
    }
    float mu   = s * (1.0f / EMB);
    float var  = s2 * (1.0f / EMB) - mu * mu;
    float rstd = rsqrtf(var + 1e-5f);

    float2 g2 = ((const float2*)(gamma + n * EMB))[lane];
    float2 b2 = ((const float2*)(beta  + n * EMB))[lane];
    half2_ o;
    o[0] = (_Float16)((v.x - mu) * rstd * g2.x + b2.x);
    o[1] = (_Float16)((v.y - mu) * rstd * g2.y + b2.y);
    ((half2_*)(qn + (size_t)row * EMB))[lane] = o;
}

// ------- transpose + f32->f16: src [R][C] -> dst [C][R], half4 stores -------
__global__ __launch_bounds__(256) void transpose_cvt(const float* __restrict__ src,
                                                     _Float16* __restrict__ dst,
                                                     int R, int C)
{
    __shared__ float tile[32][33];
    const int band = blockIdx.z;
    src += (size_t)band * R * C;
    dst += (size_t)band * R * C;
    int tx = threadIdx.x & 31, ty = threadIdx.x >> 5;
    int c0 = blockIdx.x * 32, r0 = blockIdx.y * 32;
    int c = c0 + tx;
    if (c < C) {
        #pragma unroll
        for (int i = 0; i < 4; ++i)
            tile[ty + i * 8][tx] = src[(size_t)(r0 + ty + i * 8) * C + c];   // tile[rl][cl]
    }
    __syncthreads();
    int cl = threadIdx.x >> 3, rq = (threadIdx.x & 7) * 4;
    int cw = c0 + cl;
    if (cw < C) {
        half4 v;
        #pragma unroll
        for (int j = 0; j < 4; ++j) v[j] = (_Float16)tile[rq + j][cl];
        *(half4*)(dst + (size_t)cw * R + r0 + rq) = v;
    }
}

// ---------------- GEMM1 (MFMA f16): qn(4096x128) @ W1T^T -> tanh -> h f16 ----------------
__global__ __launch_bounds__(256) void gemm1_mfma(const _Float16* __restrict__ qn,
                                                  const _Float16* __restrict__ W1T,
                                                  const float* __restrict__ b1,
                                                  _Float16* __restrict__ h)
{
    __shared__ _Float16 sA[128 * 64];
    __shared__ _Float16 sB[128 * 64];
    const int n   = blockIdx.z;
    const int m0  = blockIdx.y * 128;
    const int n0  = blockIdx.x * 128;
    const int tid = threadIdx.x;
    const int lane = tid & 63;
    const int wave = tid >> 6;
    const int wr = (wave >> 1) * 64;
    const int wc = (wave & 1) * 64;
    const int b = m0 >> 11, t0 = m0 & (TLEN - 1);

    const _Float16* Ab = qn  + ((size_t)(b * NB + n) * TLEN + t0) * EMB;
    const _Float16* Bb = W1T + ((size_t)n * MLP + n0) * EMB;

    floatx4 acc[4][4] = {};

    const int lrow = lane & 15;
    const int q16  = (lane >> 4) << 4;
    const int swz  = (lane & 7) << 4;

    for (int k0 = 0; k0 < EMB; k0 += 64) {
        #pragma unroll
        for (int i = 0; i < 4; ++i) {
            int g = tid + i * 256;
            int r = g >> 3, kb = g & 7;
            int sk = kb ^ (r & 7);
            GLOAD_LDS(Ab + (size_t)r * EMB + k0 + sk * 8, sA + g * 8);
            GLOAD_LDS(Bb + (size_t)r * EMB + k0 + sk * 8, sB + g * 8);
        }
        __syncthreads();
        #pragma unroll
        for (int kk = 0; kk < 2; ++kk) {
            half8 af[4], bf[4];
            #pragma unroll
            for (int m = 0; m < 4; ++m) {
                int r = wr + m * 16 + lrow;
                af[m] = *(const half8*)((const char*)sA + r * 128 + (((kk << 6) | q16) ^ swz));
            }
            #pragma unroll
            for (int nf = 0; nf < 4; ++nf) {
                int r = wc + nf * 16 + lrow;
                bf[nf] = *(const half8*)((const char*)sB + r * 128 + (((kk << 6) | q16) ^ swz));
            }
            #pragma unroll
            for (int m = 0; m < 4; ++m)
                #pragma unroll
                for (int nf = 0; nf < 4; ++nf)
                    acc[m][nf] = __builtin_amdgcn_mfma_f32_16x16x32_f16(af[m], bf[nf], acc[m][nf], 0, 0, 0);
        }
        __syncthreads();
    }

    const int rq = (lane >> 4) * 4;
    _Float16* hb = h + ((size_t)(b * NB + n) * TLEN + t0) * MLP;
    #pragma unroll
    for (int nf = 0; nf < 4; ++nf) {
        int col = n0 + wc + nf * 16 + lrow;
        float bias = b1[n * MLP + col];
        #pragma unroll
        for (int m = 0; m < 4; ++m) {
            int rbase = wr + m * 16 + rq;
            #pragma unroll
            for (int r = 0; r < 4; ++r) {
                float v = tanhf(acc[m][nf][r] + bias);
                hb[(size_t)(rbase + r) * MLP + col] = (_Float16)v;
            }
        }
    }
}

// ---- GEMM2 deep-pipelined: 256 rows x (64a+64g), BK=64, ring-3 LDS, counted vmcnt ----
// 8 waves (4M x 2N). Per K-tile: 2 phases x {8 ds_read_b128, 3 stage loads, barrier,
// lgkmcnt(0), setprio, 16 MFMA}. Stage issued 2 tiles ahead; vmcnt(6) per tile-ready.
__global__ __launch_bounds__(512) void gemm2_mfma(const _Float16* __restrict__ h,
                                                  const _Float16* __restrict__ W2T,
                                                  const float* __restrict__ b2,
                                                  const float* __restrict__ fw,
                                                  _Float16* __restrict__ mws)
{
    __shared__ _Float16 sA[3 * 256 * 64];   // 3 x 32 KB
    __shared__ _Float16 sB[3 * 128 * 64];   // 3 x 16 KB (Ba rows 0-63, Bg rows 64-127)

    const int NWG = 9 * 16 * NB;            // 2160, %8==0 -> bijective XCD swizzle
    int flat = blockIdx.x;
    int wg   = (flat & 7) * (NWG / 8) + (flat >> 3);
    int bx   = wg % 9;
    int tmp  = wg / 9;
    int by   = tmp & 15;
    int n    = tmp >> 4;

    const int m0  = by * 256;
    const int n0  = bx * 64;
    const int tid = threadIdx.x;
    const int lane = tid & 63;
    const int wave = tid >> 6;
    const int wm = (wave >> 1) * 64;
    const int wc = (wave & 1) * 32;
    const int b = m0 >> 11, t0 = m0 & (TLEN - 1);

    const _Float16* Ab  = h   + ((size_t)(b * NB + n) * TLEN + t0) * MLP;
    const _Float16* W2n = W2T + (size_t)n * O2 * MLP;

    floatx4 accA[4][2] = {};
    floatx4 accG[4][2] = {};

    const int lrow = lane & 15;
    const int q16  = (lane >> 4) << 4;
    const int swz  = (lane & 7) << 4;

    // --- staging lambdas (3 global_load_lds per thread per phase, 6 per tile) ---
    auto stageA2 = [&](int slot, int k0, int i0) {
        #pragma unroll
        for (int i = i0; i < i0 + 2; ++i) {
            int g = tid + i * 512;
            int r = g >> 3;
            int sk = (g & 7) ^ (r & 7);
            GLOAD_LDS(Ab + (size_t)r * MLP + k0 + sk * 8, sA + slot * 16384 + g * 8);
        }
    };
    auto stageBa = [&](int slot, int k0) {
        int g = tid, r = g >> 3;
        int sk = (g & 7) ^ (r & 7);
        int ra = n0 + r; if (ra > OUTC - 1) ra = OUTC - 1;
        GLOAD_LDS(W2n + (size_t)ra * MLP + k0 + sk * 8, sB + slot * 8192 + g * 8);
    };
    auto stageBg = [&](int slot, int k0) {
        int g = tid, r = g >> 3;
        int sk = (g & 7) ^ (r & 7);
        int rg = OUTC + n0 + r; if (rg > O2 - 1) rg = O2 - 1;
        GLOAD_LDS(W2n + (size_t)rg * MLP + k0 + sk * 8, sB + slot * 8192 + 4096 + g * 8);
    };

    // prologue: tiles 0 and 1 fully in flight (12 loads/thread)
    stageA2(0, 0, 0);  stageBa(0, 0);
    stageA2(0, 0, 2);  stageBg(0, 0);
    stageA2(1, 64, 0); stageBa(1, 64);
    stageA2(1, 64, 2); stageBg(1, 64);

    for (int kt = 0; kt < 8; ++kt) {
        // ---- tile-ready: drain the oldest 6 loads (tile kt), keep newer in flight ----
        if (kt < 7) asm volatile("s_waitcnt vmcnt(6)" ::: "memory");
        else        asm volatile("s_waitcnt vmcnt(0)" ::: "memory");
        __builtin_amdgcn_sched_barrier(0);
        __builtin_amdgcn_s_barrier();
        __builtin_amdgcn_sched_barrier(0);

        const int cur = kt % 3;
        const int kt2 = kt + 2;
        const int pre = kt2 % 3;
        const int kp  = kt2 * 64;
        const bool ds = kt2 < 8;
        const _Float16* sAc = sA + cur * 16384;
        const _Float16* sBc = sB + cur * 8192;

        #pragma unroll
        for (int kk = 0; kk < 2; ++kk) {
            half8 af[4], ba[2], bg[2];
            const int koff = (kk << 6) | q16;
            #pragma unroll
            for (int m = 0; m < 4; ++m)
                af[m] = *(const half8*)((const char*)sAc + (wm + m * 16 + lrow) * 128 + (koff ^ swz));
            #pragma unroll
            for (int nf = 0; nf < 2; ++nf) {
                ba[nf] = *(const half8*)((const char*)sBc + (wc + nf * 16 + lrow) * 128 + (koff ^ swz));
                bg[nf] = *(const half8*)((const char*)sBc + 8192 + (wc + nf * 16 + lrow) * 128 + (koff ^ swz));
            }
            if (ds) {
                if (kk == 0) { stageA2(pre, kp, 0); stageBa(pre, kp); }
                else         { stageA2(pre, kp, 2); stageBg(pre, kp); }
            }
            __builtin_amdgcn_sched_barrier(0);
            __builtin_amdgcn_s_barrier();
            asm volatile("s_waitcnt lgkmcnt(0)" ::: "memory");
            __builtin_amdgcn_sched_barrier(0);
            __builtin_amdgcn_s_setprio(1);
            #pragma unroll
            for (int m = 0; m < 4; ++m)
                #pragma unroll
                for (int nf = 0; nf < 2; ++nf) {
                    accA[m][nf] = __builtin_amdgcn_mfma_f32_16x16x32_f16(af[m], ba[nf], accA[m][nf], 0, 0, 0);
                    accG[m][nf] = __builtin_amdgcn_mfma_f32_16x16x32_f16(af[m], bg[nf], accG[m][nf], 0, 0, 0);
                }
            __builtin_amdgcn_s_setprio(0);
            __builtin_amdgcn_sched_barrier(0);
            if (kk == 0) __builtin_amdgcn_s_barrier();   // phase boundary (end barrier of
                                                         // phase 1 is next iter's ready barrier)
        }
    }

    const int rq = (lane >> 4) * 4;
    const float* b2n = b2 + n * O2;
    #pragma unroll
    for (int nf = 0; nf < 2; ++nf) {
        int c = n0 + wc + nf * 16 + lrow;
        bool valid = c < OUTC;
        int cl = valid ? c : OUTC - 1;
        float biasA = b2n[cl];
        float biasG = b2n[OUTC + cl];
        int rem = cl % 258;
        float w = fw[n * BWID + (rem >> 1)];
        _Float16* mb = mws + ((size_t)((b * NB + n) * OUTC + cl)) * TLEN + t0;
        #pragma unroll
        for (int m = 0; m < 4; ++m) {
            int tb = wm + m * 16 + rq;
            half4 vals;
            #pragma unroll
            for (int r = 0; r < 4; ++r) {
                float a = accA[m][nf][r] + biasA;
                float g = accG[m][nf][r] + biasG;
                vals[r] = (_Float16)(a * w / (1.0f + expf(-g)));
            }
            if (valid) *(half4*)(mb + tb) = vals;
        }
    }
}

// ---------------- gather: vectorized, 8 t-values per thread ----------------
__global__ __launch_bounds__(256) void gather_masks(const _Float16* __restrict__ mws,
                                                    float* __restrict__ out)
{
    const int f  = blockIdx.x;
    const int bc = blockIdx.y;
    const int b  = bc >> 1, cc = bc & 1;
    int nlo = (f >= 129) ? ((f - 65) >> 6) : 0;
    int nhi = f >> 6; if (nhi > 14) nhi = 14;
    const int t0 = threadIdx.x * 8;

    float a[8] = {0,0,0,0,0,0,0,0};
    float g[8] = {0,0,0,0,0,0,0,0};
    for (int nn = nlo; nn <= nhi; ++nn) {
        int bw = f - (nn << 6);
        int cbase = cc * 258 + (bw << 1);
        const _Float16* p = mws + ((size_t)((b * NB + nn) * OUTC + cbase)) * TLEN + t0;
        half8 va = *(const half8*)p;
        half8 vg = *(const half8*)(p + TLEN);
        #pragma unroll
        for (int j = 0; j < 8; ++j) { a[j] += (float)va[j]; g[j] += (float)vg[j]; }
    }
    float* ob = out + (((size_t)bc * NFREQ + f) * TLEN + t0) * REIM;
    #pragma unroll
    for (int j = 0; j < 4; ++j) {
        float4 v = make_float4(a[2*j], g[2*j], a[2*j+1], g[2*j+1]);
        *(float4*)(ob + j * 4) = v;
    }
}

extern "C" void kernel_launch(void* const* d_in, const int* in_sizes, int n_in,
                              void* d_out, int out_size, void* d_ws, size_t ws_size,
                              hipStream_t stream) {
    const float* q     = (const float*)d_in[0];
    const float* gamma = (const float*)d_in[1];
    const float* beta  = (const float*)d_in[2];
    const float* W1    = (const float*)d_in[3];
    const float* b1    = (const float*)d_in[4];
    const float* W2    = (const float*)d_in[5];
    const float* b2    = (const float*)d_in[6];
    const float* fw    = (const float*)d_in[7];

    _Float16* hws  = (_Float16*)d_ws;
    _Float16* mws  = hws + (size_t)RTOT * MLP;
    _Float16* qnws = mws + (size_t)BATCH * NB * OUTC * TLEN;
    _Float16* W1T  = qnws + (size_t)RTOT * EMB;
    _Float16* W2T  = qnws;                       // alias (qn dead after gemm1)

    ln_kernel<<<RTOT / 4, 256, 0, stream>>>(q, gamma, beta, qnws);
    transpose_cvt<<<dim3(16, 4, NB), 256, 0, stream>>>(W1, W1T, EMB, MLP);
    gemm1_mfma<<<dim3(4, 32, NB), 256, 0, stream>>>(qnws, W1T, b1, hws);
    transpose_cvt<<<dim3(33, 16, NB), 256, 0, stream>>>(W2, W2T, MLP, O2);
    gemm2_mfma<<<9 * 16 * NB, 512, 0, stream>>>(hws, W2T, b2, fw, mws);
    gather_masks<<<dim3(NFREQ, BATCH * CCH), 256, 0, stream>>>(mws, (float*)d_out);
}